// Round 1
// baseline (503.578 us; speedup 1.0000x reference)
//
#include <hip/hip_runtime.h>
#include <hip/hip_bf16.h>
#include <math.h>

#define NN 100000
#define EE 600000
#define FF 64
#define HH 128
#define CHUNK 1024
#define NCHUNK ((NN + CHUNK - 1) / CHUNK)   // 98

// ---------------- CSR build ----------------

__global__ void count_k(const int* __restrict__ col, int* __restrict__ cnt) {
    int e = blockIdx.x * 256 + threadIdx.x;
    if (e < EE) atomicAdd(&cnt[col[e]], 1);
}

__global__ void dinv1_k(const int* __restrict__ cnt, float* __restrict__ dinv1) {
    int c = blockIdx.x * 256 + threadIdx.x;
    if (c < NN) dinv1[c] = rsqrtf((float)cnt[c] + 1.0f);
}

__global__ void chunksum_k(const int* __restrict__ cnt, int* __restrict__ chunk_sum) {
    int b = blockIdx.x, t = threadIdx.x;
    int base = b * CHUNK + t * 4;
    int s = 0;
    #pragma unroll
    for (int i = 0; i < 4; i++) { int idx = base + i; if (idx < NN) s += cnt[idx]; }
    __shared__ int sm[4];
    for (int d = 32; d > 0; d >>= 1) s += __shfl_down(s, d);
    if ((t & 63) == 0) sm[t >> 6] = s;
    __syncthreads();
    if (t == 0) chunk_sum[b] = sm[0] + sm[1] + sm[2] + sm[3];
}

__global__ void chunkoff_k(const int* __restrict__ chunk_sum, int* __restrict__ chunk_off,
                           int* __restrict__ col_ptr) {
    if (threadIdx.x == 0) {
        int run = 0;
        for (int i = 0; i < NCHUNK; i++) { chunk_off[i] = run; run += chunk_sum[i]; }
        col_ptr[NN] = run;   // == EE
    }
}

__global__ void colptr_k(const int* __restrict__ cnt, const int* __restrict__ chunk_off,
                         int* __restrict__ col_ptr) {
    int b = blockIdx.x, t = threadIdx.x;
    int base = b * CHUNK + t * 4;
    int c[4]; int tot = 0;
    #pragma unroll
    for (int i = 0; i < 4; i++) { int idx = base + i; c[i] = (idx < NN) ? cnt[idx] : 0; tot += c[i]; }
    __shared__ int s[256];
    s[t] = tot;
    __syncthreads();
    for (int d = 1; d < 256; d <<= 1) {
        int v = (t >= d) ? s[t - d] : 0;
        __syncthreads();
        s[t] += v;
        __syncthreads();
    }
    int excl = s[t] - tot;
    int off = chunk_off[b] + excl;
    int pre = 0;
    #pragma unroll
    for (int i = 0; i < 4; i++) {
        int idx = base + i;
        if (idx < NN) col_ptr[idx] = off + pre;
        pre += c[i];
    }
}

__global__ void fill_k(const int* __restrict__ row, const int* __restrict__ col,
                       const int* __restrict__ col_ptr, int* __restrict__ cursor,
                       int* __restrict__ csr_src) {
    int e = blockIdx.x * 256 + threadIdx.x;
    if (e < EE) {
        int c = col[e];
        int slot = col_ptr[c] + atomicAdd(&cursor[c], 1);
        csr_src[slot] = row[e];
    }
}

// ---------------- tiny GEMV: vs = Wg @ att_src, vd = Wg @ att_dst ----------------

__global__ void gemv_vsvd_k(const float* __restrict__ Wg, const float* __restrict__ att_src,
                            const float* __restrict__ att_dst, float* __restrict__ vs,
                            float* __restrict__ vd) {
    int i = threadIdx.x;
    if (i < HH) {
        float s1 = 0.f, s2 = 0.f;
        for (int j = 0; j < HH; j++) {
            float w = Wg[i * HH + j];
            s1 += w * att_src[j];
            s2 += w * att_dst[j];
        }
        vs[i] = s1;
        vd[i] = s2;
    }
}

// ---------------- fp32 tiled GEMM: C[M x NCOL] = A[M x K] @ W[K x NCOL] (+bias) ----------------

template <int K, int NCOL>
__global__ __launch_bounds__(256) void gemm_k(const float* __restrict__ A, const float* __restrict__ W,
                                              const float* __restrict__ bias, float* __restrict__ C,
                                              int M) {
    constexpr int BM = 128, BN = 64, KC = 32;
    __shared__ float As[KC][132];   // transposed A-tile, padded for 16B alignment
    __shared__ float Ws[KC][BN];
    int tid = threadIdx.x;
    int bm0 = blockIdx.x * BM, bn0 = blockIdx.y * BN;
    int ty = tid >> 4, tx = tid & 15;
    float acc[8][4] = {};
    for (int kc = 0; kc < K; kc += KC) {
        {
            int rl = tid >> 3;            // 0..31
            int kk4 = (tid & 7) << 2;     // 0,4,...,28
            #pragma unroll
            for (int r8 = 0; r8 < 4; r8++) {
                int rowl = rl + r8 * 32;
                int grow = bm0 + rowl;
                float4 v = make_float4(0.f, 0.f, 0.f, 0.f);
                if (grow < M) v = *(const float4*)&A[(size_t)grow * K + kc + kk4];
                As[kk4 + 0][rowl] = v.x;
                As[kk4 + 1][rowl] = v.y;
                As[kk4 + 2][rowl] = v.z;
                As[kk4 + 3][rowl] = v.w;
            }
        }
        {
            int c4 = (tid & 15) << 2;
            #pragma unroll
            for (int h = 0; h < 2; h++) {
                int kk = (tid >> 4) + h * 16;
                *(float4*)&Ws[kk][c4] = *(const float4*)&W[(size_t)(kc + kk) * NCOL + bn0 + c4];
            }
        }
        __syncthreads();
        #pragma unroll
        for (int kk = 0; kk < KC; kk++) {
            float4 w4 = *(float4*)&Ws[kk][tx << 2];
            float4 a0 = *(float4*)&As[kk][ty << 3];
            float4 a1 = *(float4*)&As[kk][(ty << 3) + 4];
            float a[8] = {a0.x, a0.y, a0.z, a0.w, a1.x, a1.y, a1.z, a1.w};
            float wv[4] = {w4.x, w4.y, w4.z, w4.w};
            #pragma unroll
            for (int i = 0; i < 8; i++)
                #pragma unroll
                for (int j = 0; j < 4; j++) acc[i][j] += a[i] * wv[j];
        }
        __syncthreads();
    }
    float4 bv = make_float4(0.f, 0.f, 0.f, 0.f);
    if (bias) bv = *(const float4*)&bias[bn0 + (tx << 2)];
    #pragma unroll
    for (int i = 0; i < 8; i++) {
        int grow = bm0 + (ty << 3) + i;
        if (grow < M) {
            float4 o;
            o.x = acc[i][0] + bv.x;
            o.y = acc[i][1] + bv.y;
            o.z = acc[i][2] + bv.z;
            o.w = acc[i][3] + bv.w;
            *(float4*)&C[(size_t)grow * NCOL + bn0 + (tx << 2)] = o;
        }
    }
}

// ---------------- GCN aggregation (wave per node), layer1 fuses a_s/a_d ----------------

template <int LAYER>
__global__ __launch_bounds__(256) void aggregate_k(
    const float* __restrict__ xw, const int* __restrict__ col_ptr, const int* __restrict__ csr_src,
    const float* __restrict__ alpha, const float* __restrict__ dinv, const float* __restrict__ bias,
    float* __restrict__ xout, const float* __restrict__ vs, const float* __restrict__ vd,
    float* __restrict__ a_s, float* __restrict__ a_d) {
    int wid = threadIdx.x >> 6, lane = threadIdx.x & 63;
    int c = blockIdx.x * 4 + wid;
    if (c >= NN) return;
    int beg = col_ptr[c], end = col_ptr[c + 1];
    float dc = dinv[c];
    float2 acc = make_float2(0.f, 0.f);
    for (int p = beg; p < end; p++) {
        int r = csr_src[p];
        float w = (LAYER == 1) ? dinv[r] * dc : dinv[r] * alpha[p] * dc;
        float2 v = *(const float2*)&xw[(size_t)r * HH + lane * 2];
        acc.x += v.x * w;
        acc.y += v.y * w;
    }
    {   // self loop, weight 1
        float2 v = *(const float2*)&xw[(size_t)c * HH + lane * 2];
        float w = dc * dc;
        acc.x += v.x * w;
        acc.y += v.y * w;
    }
    acc.x += bias[lane * 2];
    acc.y += bias[lane * 2 + 1];
    acc.x = fmaxf(acc.x, 0.f);
    acc.y = fmaxf(acc.y, 0.f);
    *(float2*)&xout[(size_t)c * HH + lane * 2] = acc;
    if (LAYER == 1) {
        float s1 = acc.x * vs[lane * 2] + acc.y * vs[lane * 2 + 1];
        float s2 = acc.x * vd[lane * 2] + acc.y * vd[lane * 2 + 1];
        for (int d = 32; d > 0; d >>= 1) {
            s1 += __shfl_down(s1, d);
            s2 += __shfl_down(s2, d);
        }
        if (lane == 0) {
            a_s[c] = s1;
            a_d[c] = s2;
        }
    }
}

// ---------------- attention: per-node softmax over incoming edges + self ----------------

__global__ void attn_k(const int* __restrict__ col_ptr, const int* __restrict__ csr_src,
                       const float* __restrict__ a_s, const float* __restrict__ a_d,
                       float* __restrict__ alpha, float* __restrict__ dinv2) {
    int c = blockIdx.x * 256 + threadIdx.x;
    if (c >= NN) return;
    int beg = col_ptr[c], end = col_ptr[c + 1];
    float ad = a_d[c];
    float es = a_s[c] + ad;
    es = (es > 0.f) ? es : 0.2f * es;
    float m = es;
    for (int p = beg; p < end; p++) {
        float e = a_s[csr_src[p]] + ad;
        e = (e > 0.f) ? e : 0.2f * e;
        alpha[p] = e;
        m = fmaxf(m, e);
    }
    float exs = expf(es - m);
    float s = exs;
    for (int p = beg; p < end; p++) {
        float ex = expf(alpha[p] - m);
        alpha[p] = ex;
        s += ex;
    }
    float inv = 1.f / s;
    for (int p = beg; p < end; p++) alpha[p] *= inv;
    // deg2 = sum(alpha_in) + 1 = (1 - alpha_self) + 1
    dinv2[c] = rsqrtf(2.f - exs * inv);
}

// ---------------- launch ----------------

extern "C" void kernel_launch(void* const* d_in, const int* in_sizes, int n_in,
                              void* d_out, int out_size, void* d_ws, size_t ws_size,
                              hipStream_t stream) {
    const float* x = (const float*)d_in[0];
    const int* eidx = (const int*)d_in[1];     // [2][E]: row, col
    const float* W0 = (const float*)d_in[3];
    const float* b0 = (const float*)d_in[4];
    const float* Wg = (const float*)d_in[5];
    const float* att_src = (const float*)d_in[6];
    const float* att_dst = (const float*)d_in[7];
    const float* W1 = (const float*)d_in[8];
    const float* b1 = (const float*)d_in[9];
    const float* W2 = (const float*)d_in[10];
    const float* b2 = (const float*)d_in[11];
    const float* Wr = (const float*)d_in[12];
    const float* br = (const float*)d_in[13];
    float* out = (float*)d_out;

    const int* erow = eidx;
    const int* ecol = eidx + EE;

    char* p = (char*)d_ws;
    auto alloc = [&](size_t bytes) {
        void* r = (void*)p;
        p += (bytes + 255) & ~(size_t)255;
        return r;
    };
    int* col_ptr = (int*)alloc((NN + 1) * sizeof(int));
    int* csr_src = (int*)alloc(EE * sizeof(int));
    int* cnt = (int*)alloc(NN * sizeof(int));
    int* cursor = (int*)alloc(NN * sizeof(int));
    int* chunk_sum = (int*)alloc(128 * sizeof(int));
    int* chunk_off = (int*)alloc(128 * sizeof(int));
    float* alpha = (float*)alloc(EE * sizeof(float));
    float* dinv1 = (float*)alloc(NN * sizeof(float));
    float* dinv2 = (float*)alloc(NN * sizeof(float));
    float* a_s = (float*)alloc(NN * sizeof(float));
    float* a_d = (float*)alloc(NN * sizeof(float));
    float* vs = (float*)alloc(HH * sizeof(float));
    float* vd = (float*)alloc(HH * sizeof(float));
    float* bufA = (float*)alloc((size_t)NN * HH * sizeof(float));
    float* bufB = (float*)alloc((size_t)NN * HH * sizeof(float));

    hipMemsetAsync(cnt, 0, NN * sizeof(int), stream);
    hipMemsetAsync(cursor, 0, NN * sizeof(int), stream);

    count_k<<<(EE + 255) / 256, 256, 0, stream>>>(ecol, cnt);
    dinv1_k<<<(NN + 255) / 256, 256, 0, stream>>>(cnt, dinv1);
    chunksum_k<<<NCHUNK, 256, 0, stream>>>(cnt, chunk_sum);
    chunkoff_k<<<1, 64, 0, stream>>>(chunk_sum, chunk_off, col_ptr);
    colptr_k<<<NCHUNK, 256, 0, stream>>>(cnt, chunk_off, col_ptr);
    fill_k<<<(EE + 255) / 256, 256, 0, stream>>>(erow, ecol, col_ptr, cursor, csr_src);
    gemv_vsvd_k<<<1, 128, 0, stream>>>(Wg, att_src, att_dst, vs, vd);

    dim3 g1((NN + 127) / 128, HH / 64);
    dim3 gr((NN + 127) / 128, FF / 64);
    int aggGrid = (NN + 3) / 4;

    // layer 1: bufA = x @ W0 ; bufB = x1 = relu(agg(bufA)) ; fused a_s/a_d
    gemm_k<FF, HH><<<g1, 256, 0, stream>>>(x, W0, nullptr, bufA, NN);
    aggregate_k<1><<<aggGrid, 256, 0, stream>>>(bufA, col_ptr, csr_src, nullptr, dinv1, b0, bufB,
                                                vs, vd, a_s, a_d);
    // attention coefficients
    attn_k<<<(NN + 255) / 256, 256, 0, stream>>>(col_ptr, csr_src, a_s, a_d, alpha, dinv2);
    // layer 2: bufA = x1 @ W1 ; bufB = x2
    gemm_k<HH, HH><<<g1, 256, 0, stream>>>(bufB, W1, nullptr, bufA, NN);
    aggregate_k<2><<<aggGrid, 256, 0, stream>>>(bufA, col_ptr, csr_src, alpha, dinv2, b1, bufB,
                                                nullptr, nullptr, nullptr, nullptr);
    // layer 3: bufA = x2 @ W2 ; bufB = x3
    gemm_k<HH, HH><<<g1, 256, 0, stream>>>(bufB, W2, nullptr, bufA, NN);
    aggregate_k<2><<<aggGrid, 256, 0, stream>>>(bufA, col_ptr, csr_src, alpha, dinv2, b2, bufB,
                                                nullptr, nullptr, nullptr, nullptr);
    // readout: out = x3 @ Wr + br  (output layout == (G,L,F) flattened)
    gemm_k<HH, FF><<<gr, 256, 0, stream>>>(bufB, Wr, br, out, NN);
}

// Round 2
// 475.362 us; speedup vs baseline: 1.0594x; 1.0594x over previous
//
#include <hip/hip_runtime.h>
#include <hip/hip_bf16.h>
#include <math.h>

#define NN 100000
#define EE 600000
#define FF 64
#define HH 128
#define CHUNK 1024
#define NCHUNK ((NN + CHUNK - 1) / CHUNK)   // 98

// ---------------- CSR build ----------------

__global__ void count_k(const int* __restrict__ col, int* __restrict__ cnt) {
    int e = blockIdx.x * 256 + threadIdx.x;
    if (e < EE) atomicAdd(&cnt[col[e]], 1);
}

__global__ void dinv1_k(const int* __restrict__ cnt, float* __restrict__ dinv1) {
    int c = blockIdx.x * 256 + threadIdx.x;
    if (c < NN) dinv1[c] = rsqrtf((float)cnt[c] + 1.0f);
}

__global__ void chunksum_k(const int* __restrict__ cnt, int* __restrict__ chunk_sum) {
    int b = blockIdx.x, t = threadIdx.x;
    int base = b * CHUNK + t * 4;
    int s = 0;
    #pragma unroll
    for (int i = 0; i < 4; i++) { int idx = base + i; if (idx < NN) s += cnt[idx]; }
    __shared__ int sm[4];
    for (int d = 32; d > 0; d >>= 1) s += __shfl_down(s, d);
    if ((t & 63) == 0) sm[t >> 6] = s;
    __syncthreads();
    if (t == 0) chunk_sum[b] = sm[0] + sm[1] + sm[2] + sm[3];
}

__global__ void chunkoff_k(const int* __restrict__ chunk_sum, int* __restrict__ chunk_off,
                           int* __restrict__ col_ptr) {
    if (threadIdx.x == 0) {
        int run = 0;
        for (int i = 0; i < NCHUNK; i++) { chunk_off[i] = run; run += chunk_sum[i]; }
        col_ptr[NN] = run;   // == EE
    }
}

__global__ void colptr_k(const int* __restrict__ cnt, const int* __restrict__ chunk_off,
                         int* __restrict__ col_ptr) {
    int b = blockIdx.x, t = threadIdx.x;
    int base = b * CHUNK + t * 4;
    int c[4]; int tot = 0;
    #pragma unroll
    for (int i = 0; i < 4; i++) { int idx = base + i; c[i] = (idx < NN) ? cnt[idx] : 0; tot += c[i]; }
    __shared__ int s[256];
    s[t] = tot;
    __syncthreads();
    for (int d = 1; d < 256; d <<= 1) {
        int v = (t >= d) ? s[t - d] : 0;
        __syncthreads();
        s[t] += v;
        __syncthreads();
    }
    int excl = s[t] - tot;
    int off = chunk_off[b] + excl;
    int pre = 0;
    #pragma unroll
    for (int i = 0; i < 4; i++) {
        int idx = base + i;
        if (idx < NN) col_ptr[idx] = off + pre;
        pre += c[i];
    }
}

__global__ void fill_k(const int* __restrict__ row, const int* __restrict__ col,
                       const int* __restrict__ col_ptr, int* __restrict__ cursor,
                       int* __restrict__ csr_src) {
    int e = blockIdx.x * 256 + threadIdx.x;
    if (e < EE) {
        int c = col[e];
        int slot = col_ptr[c] + atomicAdd(&cursor[c], 1);
        csr_src[slot] = row[e];
    }
}

// ---------------- tiny GEMV: vs = Wg @ att_src, vd = Wg @ att_dst ----------------

__global__ void gemv_vsvd_k(const float* __restrict__ Wg, const float* __restrict__ att_src,
                            const float* __restrict__ att_dst, float* __restrict__ vs,
                            float* __restrict__ vd) {
    int i = threadIdx.x;
    if (i < HH) {
        float s1 = 0.f, s2 = 0.f;
        for (int j = 0; j < HH; j++) {
            float w = Wg[i * HH + j];
            s1 += w * att_src[j];
            s2 += w * att_dst[j];
        }
        vs[i] = s1;
        vd[i] = s2;
    }
}

// ---------------- fp32 tiled GEMM: C[M x NCOL] = A[M x K] @ W[K x NCOL] (+bias) ----------------

template <int K, int NCOL>
__global__ __launch_bounds__(256) void gemm_k(const float* __restrict__ A, const float* __restrict__ W,
                                              const float* __restrict__ bias, float* __restrict__ C,
                                              int M) {
    constexpr int BM = 128, BN = 64, KC = 32;
    __shared__ float As[KC][132];   // transposed A-tile, padded for 16B alignment
    __shared__ float Ws[KC][BN];
    int tid = threadIdx.x;
    int bm0 = blockIdx.x * BM, bn0 = blockIdx.y * BN;
    int ty = tid >> 4, tx = tid & 15;
    float acc[8][4] = {};
    for (int kc = 0; kc < K; kc += KC) {
        {
            int rl = tid >> 3;            // 0..31
            int kk4 = (tid & 7) << 2;     // 0,4,...,28
            #pragma unroll
            for (int r8 = 0; r8 < 4; r8++) {
                int rowl = rl + r8 * 32;
                int grow = bm0 + rowl;
                float4 v = make_float4(0.f, 0.f, 0.f, 0.f);
                if (grow < M) v = *(const float4*)&A[(size_t)grow * K + kc + kk4];
                As[kk4 + 0][rowl] = v.x;
                As[kk4 + 1][rowl] = v.y;
                As[kk4 + 2][rowl] = v.z;
                As[kk4 + 3][rowl] = v.w;
            }
        }
        {
            int c4 = (tid & 15) << 2;
            #pragma unroll
            for (int h = 0; h < 2; h++) {
                int kk = (tid >> 4) + h * 16;
                *(float4*)&Ws[kk][c4] = *(const float4*)&W[(size_t)(kc + kk) * NCOL + bn0 + c4];
            }
        }
        __syncthreads();
        #pragma unroll
        for (int kk = 0; kk < KC; kk++) {
            float4 w4 = *(float4*)&Ws[kk][tx << 2];
            float4 a0 = *(float4*)&As[kk][ty << 3];
            float4 a1 = *(float4*)&As[kk][(ty << 3) + 4];
            float a[8] = {a0.x, a0.y, a0.z, a0.w, a1.x, a1.y, a1.z, a1.w};
            float wv[4] = {w4.x, w4.y, w4.z, w4.w};
            #pragma unroll
            for (int i = 0; i < 8; i++)
                #pragma unroll
                for (int j = 0; j < 4; j++) acc[i][j] += a[i] * wv[j];
        }
        __syncthreads();
    }
    float4 bv = make_float4(0.f, 0.f, 0.f, 0.f);
    if (bias) bv = *(const float4*)&bias[bn0 + (tx << 2)];
    #pragma unroll
    for (int i = 0; i < 8; i++) {
        int grow = bm0 + (ty << 3) + i;
        if (grow < M) {
            float4 o;
            o.x = acc[i][0] + bv.x;
            o.y = acc[i][1] + bv.y;
            o.z = acc[i][2] + bv.z;
            o.w = acc[i][3] + bv.w;
            *(float4*)&C[(size_t)grow * NCOL + bn0 + (tx << 2)] = o;
        }
    }
}

// ---------------- GCN aggregation: wave per node, 2 edges in flight, pipelined ----------------
// Lanes 0-31 (half 0) take even-index edges, lanes 32-63 (half 1) odd-index edges.
// Each half gathers a full 512 B row per iteration (32 lanes x float4).
// (r, w) for the next pair-iteration is prefetched so the index->weight chain
// hides under the row gather latency.

template <int LAYER>
__global__ __launch_bounds__(256) void aggregate_k(
    const float* __restrict__ xw, const int* __restrict__ col_ptr, const int* __restrict__ csr_src,
    const float* __restrict__ alpha, const float* __restrict__ dinv, const float* __restrict__ bias,
    float* __restrict__ xout, const float* __restrict__ vs, const float* __restrict__ vd,
    float* __restrict__ a_s, float* __restrict__ a_d) {
    int wid = threadIdx.x >> 6, lane = threadIdx.x & 63;
    int c = blockIdx.x * 4 + wid;
    if (c >= NN) return;
    int half = lane >> 5;
    int ch = (lane & 31) << 2;     // channel base: 0,4,...,124
    int beg = col_ptr[c], end = col_ptr[c + 1];
    float dc = dinv[c];
    float4 acc = make_float4(0.f, 0.f, 0.f, 0.f);

    int p = beg + half;
    int r = 0; float w = 0.f;
    if (p < end) {
        r = csr_src[p];
        w = (LAYER == 1) ? dinv[r] * dc : dinv[r] * alpha[p] * dc;
    }
    while (p < end) {
        int pn = p + 2;
        int rn = 0; float wn = 0.f;
        if (pn < end) {
            rn = csr_src[pn];
            wn = (LAYER == 1) ? dinv[rn] * dc : dinv[rn] * alpha[pn] * dc;
        }
        float4 v = *(const float4*)&xw[(size_t)r * HH + ch];
        acc.x += v.x * w; acc.y += v.y * w; acc.z += v.z * w; acc.w += v.w * w;
        p = pn; r = rn; w = wn;
    }
    // combine even/odd halves (lane l <-> lane l^32 hold the same channels)
    acc.x += __shfl(acc.x, lane ^ 32);
    acc.y += __shfl(acc.y, lane ^ 32);
    acc.z += __shfl(acc.z, lane ^ 32);
    acc.w += __shfl(acc.w, lane ^ 32);

    if (half == 0) {
        // self loop (weight dc*dc) + bias + relu
        float4 v = *(const float4*)&xw[(size_t)c * HH + ch];
        float ws = dc * dc;
        float4 b4 = *(const float4*)&bias[ch];
        acc.x = fmaxf(fmaf(v.x, ws, acc.x) + b4.x, 0.f);
        acc.y = fmaxf(fmaf(v.y, ws, acc.y) + b4.y, 0.f);
        acc.z = fmaxf(fmaf(v.z, ws, acc.z) + b4.z, 0.f);
        acc.w = fmaxf(fmaf(v.w, ws, acc.w) + b4.w, 0.f);
        *(float4*)&xout[(size_t)c * HH + ch] = acc;
        if (LAYER == 1) {
            float4 s4 = *(const float4*)&vs[ch];
            float4 d4 = *(const float4*)&vd[ch];
            float s1 = acc.x * s4.x + acc.y * s4.y + acc.z * s4.z + acc.w * s4.w;
            float s2 = acc.x * d4.x + acc.y * d4.y + acc.z * d4.z + acc.w * d4.w;
            for (int d = 16; d > 0; d >>= 1) {
                s1 += __shfl_down(s1, d);
                s2 += __shfl_down(s2, d);
            }
            if (lane == 0) {
                a_s[c] = s1;
                a_d[c] = s2;
            }
        }
    }
}

// ---------------- attention: per-node softmax over incoming edges + self ----------------

__global__ void attn_k(const int* __restrict__ col_ptr, const int* __restrict__ csr_src,
                       const float* __restrict__ a_s, const float* __restrict__ a_d,
                       float* __restrict__ alpha, float* __restrict__ dinv2) {
    int c = blockIdx.x * 256 + threadIdx.x;
    if (c >= NN) return;
    int beg = col_ptr[c], end = col_ptr[c + 1];
    float ad = a_d[c];
    float es = a_s[c] + ad;
    es = (es > 0.f) ? es : 0.2f * es;
    float m = es;
    for (int p = beg; p < end; p++) {
        float e = a_s[csr_src[p]] + ad;
        e = (e > 0.f) ? e : 0.2f * e;
        alpha[p] = e;
        m = fmaxf(m, e);
    }
    float exs = expf(es - m);
    float s = exs;
    for (int p = beg; p < end; p++) {
        float ex = expf(alpha[p] - m);
        alpha[p] = ex;
        s += ex;
    }
    float inv = 1.f / s;
    for (int p = beg; p < end; p++) alpha[p] *= inv;
    // deg2 = sum(alpha_in) + 1 = (1 - alpha_self) + 1
    dinv2[c] = rsqrtf(2.f - exs * inv);
}

// ---------------- launch ----------------

extern "C" void kernel_launch(void* const* d_in, const int* in_sizes, int n_in,
                              void* d_out, int out_size, void* d_ws, size_t ws_size,
                              hipStream_t stream) {
    const float* x = (const float*)d_in[0];
    const int* eidx = (const int*)d_in[1];     // [2][E]: row, col
    const float* W0 = (const float*)d_in[3];
    const float* b0 = (const float*)d_in[4];
    const float* Wg = (const float*)d_in[5];
    const float* att_src = (const float*)d_in[6];
    const float* att_dst = (const float*)d_in[7];
    const float* W1 = (const float*)d_in[8];
    const float* b1 = (const float*)d_in[9];
    const float* W2 = (const float*)d_in[10];
    const float* b2 = (const float*)d_in[11];
    const float* Wr = (const float*)d_in[12];
    const float* br = (const float*)d_in[13];
    float* out = (float*)d_out;

    const int* erow = eidx;
    const int* ecol = eidx + EE;

    char* p = (char*)d_ws;
    auto alloc = [&](size_t bytes) {
        void* r = (void*)p;
        p += (bytes + 255) & ~(size_t)255;
        return r;
    };
    int* col_ptr = (int*)alloc((NN + 1) * sizeof(int));
    int* csr_src = (int*)alloc(EE * sizeof(int));
    int* cnt = (int*)alloc(NN * sizeof(int));
    int* cursor = (int*)alloc(NN * sizeof(int));
    int* chunk_sum = (int*)alloc(128 * sizeof(int));
    int* chunk_off = (int*)alloc(128 * sizeof(int));
    float* alpha = (float*)alloc(EE * sizeof(float));
    float* dinv1 = (float*)alloc(NN * sizeof(float));
    float* dinv2 = (float*)alloc(NN * sizeof(float));
    float* a_s = (float*)alloc(NN * sizeof(float));
    float* a_d = (float*)alloc(NN * sizeof(float));
    float* vs = (float*)alloc(HH * sizeof(float));
    float* vd = (float*)alloc(HH * sizeof(float));
    float* bufA = (float*)alloc((size_t)NN * HH * sizeof(float));
    float* bufB = (float*)alloc((size_t)NN * HH * sizeof(float));

    hipMemsetAsync(cnt, 0, NN * sizeof(int), stream);
    hipMemsetAsync(cursor, 0, NN * sizeof(int), stream);

    count_k<<<(EE + 255) / 256, 256, 0, stream>>>(ecol, cnt);
    dinv1_k<<<(NN + 255) / 256, 256, 0, stream>>>(cnt, dinv1);
    chunksum_k<<<NCHUNK, 256, 0, stream>>>(cnt, chunk_sum);
    chunkoff_k<<<1, 64, 0, stream>>>(chunk_sum, chunk_off, col_ptr);
    colptr_k<<<NCHUNK, 256, 0, stream>>>(cnt, chunk_off, col_ptr);
    fill_k<<<(EE + 255) / 256, 256, 0, stream>>>(erow, ecol, col_ptr, cursor, csr_src);
    gemv_vsvd_k<<<1, 128, 0, stream>>>(Wg, att_src, att_dst, vs, vd);

    dim3 g1((NN + 127) / 128, HH / 64);
    dim3 gr((NN + 127) / 128, FF / 64);
    int aggGrid = (NN + 3) / 4;

    // layer 1: bufA = x @ W0 ; bufB = x1 = relu(agg(bufA)) ; fused a_s/a_d
    gemm_k<FF, HH><<<g1, 256, 0, stream>>>(x, W0, nullptr, bufA, NN);
    aggregate_k<1><<<aggGrid, 256, 0, stream>>>(bufA, col_ptr, csr_src, nullptr, dinv1, b0, bufB,
                                                vs, vd, a_s, a_d);
    // attention coefficients
    attn_k<<<(NN + 255) / 256, 256, 0, stream>>>(col_ptr, csr_src, a_s, a_d, alpha, dinv2);
    // layer 2: bufA = x1 @ W1 ; bufB = x2
    gemm_k<HH, HH><<<g1, 256, 0, stream>>>(bufB, W1, nullptr, bufA, NN);
    aggregate_k<2><<<aggGrid, 256, 0, stream>>>(bufA, col_ptr, csr_src, alpha, dinv2, b1, bufB,
                                                nullptr, nullptr, nullptr, nullptr);
    // layer 3: bufA = x2 @ W2 ; bufB = x3
    gemm_k<HH, HH><<<g1, 256, 0, stream>>>(bufB, W2, nullptr, bufA, NN);
    aggregate_k<2><<<aggGrid, 256, 0, stream>>>(bufA, col_ptr, csr_src, alpha, dinv2, b2, bufB,
                                                nullptr, nullptr, nullptr, nullptr);
    // readout: out = x3 @ Wr + br  (output layout == (G,L,F) flattened)
    gemm_k<HH, FF><<<gr, 256, 0, stream>>>(bufB, Wr, br, out, NN);
}

// Round 3
// 427.608 us; speedup vs baseline: 1.1777x; 1.1117x over previous
//
#include <hip/hip_runtime.h>
#include <hip/hip_bf16.h>
#include <math.h>

#define NN 100000
#define EE 600000
#define FF 64
#define HH 128
#define CHUNK 1024
#define NCHUNK ((NN + CHUNK - 1) / CHUNK)   // 98

typedef unsigned short u16;

__device__ __forceinline__ u16 f2bf(float f) {
    __hip_bfloat16 h = __float2bfloat16(f);
    return *(u16*)&h;
}
__device__ __forceinline__ float bf2f(u16 u) {
    unsigned int t = ((unsigned int)u) << 16;
    return *(float*)&t;
}

// ---------------- CSR build ----------------

__global__ void count_k(const int* __restrict__ col, int* __restrict__ cnt) {
    int e = blockIdx.x * 256 + threadIdx.x;
    if (e < EE) atomicAdd(&cnt[col[e]], 1);
}

__global__ void dinv1_k(const int* __restrict__ cnt, float* __restrict__ dinv1) {
    int c = blockIdx.x * 256 + threadIdx.x;
    if (c < NN) dinv1[c] = rsqrtf((float)cnt[c] + 1.0f);
}

__global__ void chunksum_k(const int* __restrict__ cnt, int* __restrict__ chunk_sum) {
    int b = blockIdx.x, t = threadIdx.x;
    int base = b * CHUNK + t * 4;
    int s = 0;
    #pragma unroll
    for (int i = 0; i < 4; i++) { int idx = base + i; if (idx < NN) s += cnt[idx]; }
    __shared__ int sm[4];
    for (int d = 32; d > 0; d >>= 1) s += __shfl_down(s, d);
    if ((t & 63) == 0) sm[t >> 6] = s;
    __syncthreads();
    if (t == 0) chunk_sum[b] = sm[0] + sm[1] + sm[2] + sm[3];
}

__global__ void chunkoff_k(const int* __restrict__ chunk_sum, int* __restrict__ chunk_off,
                           int* __restrict__ col_ptr) {
    if (threadIdx.x == 0) {
        int run = 0;
        for (int i = 0; i < NCHUNK; i++) { chunk_off[i] = run; run += chunk_sum[i]; }
        col_ptr[NN] = run;   // == EE
    }
}

__global__ void colptr_k(const int* __restrict__ cnt, const int* __restrict__ chunk_off,
                         int* __restrict__ col_ptr) {
    int b = blockIdx.x, t = threadIdx.x;
    int base = b * CHUNK + t * 4;
    int c[4]; int tot = 0;
    #pragma unroll
    for (int i = 0; i < 4; i++) { int idx = base + i; c[i] = (idx < NN) ? cnt[idx] : 0; tot += c[i]; }
    __shared__ int s[256];
    s[t] = tot;
    __syncthreads();
    for (int d = 1; d < 256; d <<= 1) {
        int v = (t >= d) ? s[t - d] : 0;
        __syncthreads();
        s[t] += v;
        __syncthreads();
    }
    int excl = s[t] - tot;
    int off = chunk_off[b] + excl;
    int pre = 0;
    #pragma unroll
    for (int i = 0; i < 4; i++) {
        int idx = base + i;
        if (idx < NN) col_ptr[idx] = off + pre;
        pre += c[i];
    }
}

__global__ void fill_k(const int* __restrict__ row, const int* __restrict__ col,
                       const int* __restrict__ col_ptr, int* __restrict__ cursor,
                       int* __restrict__ csr_src) {
    int e = blockIdx.x * 256 + threadIdx.x;
    if (e < EE) {
        int c = col[e];
        int slot = col_ptr[c] + atomicAdd(&cursor[c], 1);
        csr_src[slot] = row[e];
    }
}

// ---------------- tiny GEMV: vs = Wg @ att_src, vd = Wg @ att_dst ----------------

__global__ void gemv_vsvd_k(const float* __restrict__ Wg, const float* __restrict__ att_src,
                            const float* __restrict__ att_dst, float* __restrict__ vs,
                            float* __restrict__ vd) {
    int i = threadIdx.x;
    if (i < HH) {
        float s1 = 0.f, s2 = 0.f;
        for (int j = 0; j < HH; j++) {
            float w = Wg[i * HH + j];
            s1 += w * att_src[j];
            s2 += w * att_dst[j];
        }
        vs[i] = s1;
        vd[i] = s2;
    }
}

// ---------------- fp32 tiled GEMM: C[M x NCOL] = A[M x K] @ W[K x NCOL] (+bias) ----------------
// OUT_BF16: C is bf16 (u16*), no bias. Otherwise C is float* (+bias).

template <int K, int NCOL, bool OUT_BF16>
__global__ __launch_bounds__(256) void gemm_k(const float* __restrict__ A, const float* __restrict__ W,
                                              const float* __restrict__ bias, void* __restrict__ Cv,
                                              int M) {
    constexpr int BM = 128, BN = 64, KC = 32;
    __shared__ float As[KC][132];   // transposed A-tile, padded
    __shared__ float Ws[KC][BN];
    int tid = threadIdx.x;
    int bm0 = blockIdx.x * BM, bn0 = blockIdx.y * BN;
    int ty = tid >> 4, tx = tid & 15;
    float acc[8][4] = {};
    for (int kc = 0; kc < K; kc += KC) {
        {
            int rl = tid >> 3;            // 0..31
            int kk4 = (tid & 7) << 2;     // 0,4,...,28
            #pragma unroll
            for (int r8 = 0; r8 < 4; r8++) {
                int rowl = rl + r8 * 32;
                int grow = bm0 + rowl;
                float4 v = make_float4(0.f, 0.f, 0.f, 0.f);
                if (grow < M) v = *(const float4*)&A[(size_t)grow * K + kc + kk4];
                As[kk4 + 0][rowl] = v.x;
                As[kk4 + 1][rowl] = v.y;
                As[kk4 + 2][rowl] = v.z;
                As[kk4 + 3][rowl] = v.w;
            }
        }
        {
            int c4 = (tid & 15) << 2;
            #pragma unroll
            for (int h = 0; h < 2; h++) {
                int kk = (tid >> 4) + h * 16;
                *(float4*)&Ws[kk][c4] = *(const float4*)&W[(size_t)(kc + kk) * NCOL + bn0 + c4];
            }
        }
        __syncthreads();
        #pragma unroll
        for (int kk = 0; kk < KC; kk++) {
            float4 w4 = *(float4*)&Ws[kk][tx << 2];
            float4 a0 = *(float4*)&As[kk][ty << 3];
            float4 a1 = *(float4*)&As[kk][(ty << 3) + 4];
            float a[8] = {a0.x, a0.y, a0.z, a0.w, a1.x, a1.y, a1.z, a1.w};
            float wv[4] = {w4.x, w4.y, w4.z, w4.w};
            #pragma unroll
            for (int i = 0; i < 8; i++)
                #pragma unroll
                for (int j = 0; j < 4; j++) acc[i][j] += a[i] * wv[j];
        }
        __syncthreads();
    }
    if (OUT_BF16) {
        u16* C = (u16*)Cv;
        #pragma unroll
        for (int i = 0; i < 8; i++) {
            int grow = bm0 + (ty << 3) + i;
            if (grow < M) {
                ushort4 o;
                o.x = f2bf(acc[i][0]);
                o.y = f2bf(acc[i][1]);
                o.z = f2bf(acc[i][2]);
                o.w = f2bf(acc[i][3]);
                *(ushort4*)&C[(size_t)grow * NCOL + bn0 + (tx << 2)] = o;
            }
        }
    } else {
        float* C = (float*)Cv;
        float4 bv = make_float4(0.f, 0.f, 0.f, 0.f);
        if (bias) bv = *(const float4*)&bias[bn0 + (tx << 2)];
        #pragma unroll
        for (int i = 0; i < 8; i++) {
            int grow = bm0 + (ty << 3) + i;
            if (grow < M) {
                float4 o;
                o.x = acc[i][0] + bv.x;
                o.y = acc[i][1] + bv.y;
                o.z = acc[i][2] + bv.z;
                o.w = acc[i][3] + bv.w;
                *(float4*)&C[(size_t)grow * NCOL + bn0 + (tx << 2)] = o;
            }
        }
    }
}

// ---------------- GCN aggregation: wave per node, bf16 rows, 4 gathers in flight ----------------
// Half h (lanes h*32..h*32+31) owns edges p ≡ h, h+2 (mod 4): two streams per half.
// Each half gathers a full 256 B bf16 row per stream iteration (32 lanes x ushort4).

template <int LAYER>
__global__ __launch_bounds__(256) void aggregate_k(
    const u16* __restrict__ xw, const int* __restrict__ col_ptr, const int* __restrict__ csr_src,
    const float* __restrict__ alpha, const float* __restrict__ dinv, const float* __restrict__ bias,
    float* __restrict__ xout, const float* __restrict__ vs, const float* __restrict__ vd,
    float* __restrict__ a_s, float* __restrict__ a_d) {
    int wid = threadIdx.x >> 6, lane = threadIdx.x & 63;
    int c = blockIdx.x * 4 + wid;
    if (c >= NN) return;
    int half = lane >> 5;
    int ch = (lane & 31) << 2;     // channel base: 0,4,...,124
    int beg = col_ptr[c], end = col_ptr[c + 1];
    float dc = dinv[c];
    float4 acc = make_float4(0.f, 0.f, 0.f, 0.f);

    int pA = beg + half;
    int pB = pA + 2;
    int rA = 0, rB = 0; float wA = 0.f, wB = 0.f;
    if (pA < end) {
        rA = csr_src[pA];
        wA = (LAYER == 1) ? dinv[rA] * dc : dinv[rA] * alpha[pA] * dc;
    }
    if (pB < end) {
        rB = csr_src[pB];
        wB = (LAYER == 1) ? dinv[rB] * dc : dinv[rB] * alpha[pB] * dc;
    }
    while (pA < end) {
        bool hb = pB < end;
        ushort4 vA = *(const ushort4*)&xw[(size_t)rA * HH + ch];
        ushort4 vB;
        if (hb) vB = *(const ushort4*)&xw[(size_t)rB * HH + ch];
        // prefetch next pair of (index, weight)
        int pA2 = pA + 4, pB2 = pB + 4;
        int rA2 = 0, rB2 = 0; float wA2 = 0.f, wB2 = 0.f;
        if (pA2 < end) {
            rA2 = csr_src[pA2];
            wA2 = (LAYER == 1) ? dinv[rA2] * dc : dinv[rA2] * alpha[pA2] * dc;
        }
        if (pB2 < end) {
            rB2 = csr_src[pB2];
            wB2 = (LAYER == 1) ? dinv[rB2] * dc : dinv[rB2] * alpha[pB2] * dc;
        }
        acc.x += bf2f(vA.x) * wA;
        acc.y += bf2f(vA.y) * wA;
        acc.z += bf2f(vA.z) * wA;
        acc.w += bf2f(vA.w) * wA;
        if (hb) {
            acc.x += bf2f(vB.x) * wB;
            acc.y += bf2f(vB.y) * wB;
            acc.z += bf2f(vB.z) * wB;
            acc.w += bf2f(vB.w) * wB;
        }
        pA = pA2; pB = pB2; rA = rA2; rB = rB2; wA = wA2; wB = wB2;
    }
    // combine even/odd halves (lane l <-> lane l^32 hold the same channels)
    acc.x += __shfl(acc.x, lane ^ 32);
    acc.y += __shfl(acc.y, lane ^ 32);
    acc.z += __shfl(acc.z, lane ^ 32);
    acc.w += __shfl(acc.w, lane ^ 32);

    if (half == 0) {
        // self loop (weight dc*dc) + bias + relu
        ushort4 v = *(const ushort4*)&xw[(size_t)c * HH + ch];
        float ws = dc * dc;
        float4 b4 = *(const float4*)&bias[ch];
        acc.x = fmaxf(fmaf(bf2f(v.x), ws, acc.x) + b4.x, 0.f);
        acc.y = fmaxf(fmaf(bf2f(v.y), ws, acc.y) + b4.y, 0.f);
        acc.z = fmaxf(fmaf(bf2f(v.z), ws, acc.z) + b4.z, 0.f);
        acc.w = fmaxf(fmaf(bf2f(v.w), ws, acc.w) + b4.w, 0.f);
        *(float4*)&xout[(size_t)c * HH + ch] = acc;
        if (LAYER == 1) {
            float4 s4 = *(const float4*)&vs[ch];
            float4 d4 = *(const float4*)&vd[ch];
            float s1 = acc.x * s4.x + acc.y * s4.y + acc.z * s4.z + acc.w * s4.w;
            float s2 = acc.x * d4.x + acc.y * d4.y + acc.z * d4.z + acc.w * d4.w;
            for (int d = 16; d > 0; d >>= 1) {
                s1 += __shfl_down(s1, d);
                s2 += __shfl_down(s2, d);
            }
            if (lane == 0) {
                a_s[c] = s1;
                a_d[c] = s2;
            }
        }
    }
}

// ---------------- attention: per-node softmax over incoming edges + self ----------------

__global__ void attn_k(const int* __restrict__ col_ptr, const int* __restrict__ csr_src,
                       const float* __restrict__ a_s, const float* __restrict__ a_d,
                       float* __restrict__ alpha, float* __restrict__ dinv2) {
    int c = blockIdx.x * 256 + threadIdx.x;
    if (c >= NN) return;
    int beg = col_ptr[c], end = col_ptr[c + 1];
    float ad = a_d[c];
    float es = a_s[c] + ad;
    es = (es > 0.f) ? es : 0.2f * es;
    float m = es;
    for (int p = beg; p < end; p++) {
        float e = a_s[csr_src[p]] + ad;
        e = (e > 0.f) ? e : 0.2f * e;
        alpha[p] = e;
        m = fmaxf(m, e);
    }
    float exs = expf(es - m);
    float s = exs;
    for (int p = beg; p < end; p++) {
        float ex = expf(alpha[p] - m);
        alpha[p] = ex;
        s += ex;
    }
    float inv = 1.f / s;
    for (int p = beg; p < end; p++) alpha[p] *= inv;
    // deg2 = sum(alpha_in) + 1 = (1 - alpha_self) + 1
    dinv2[c] = rsqrtf(2.f - exs * inv);
}

// ---------------- launch ----------------

extern "C" void kernel_launch(void* const* d_in, const int* in_sizes, int n_in,
                              void* d_out, int out_size, void* d_ws, size_t ws_size,
                              hipStream_t stream) {
    const float* x = (const float*)d_in[0];
    const int* eidx = (const int*)d_in[1];     // [2][E]: row, col
    const float* W0 = (const float*)d_in[3];
    const float* b0 = (const float*)d_in[4];
    const float* Wg = (const float*)d_in[5];
    const float* att_src = (const float*)d_in[6];
    const float* att_dst = (const float*)d_in[7];
    const float* W1 = (const float*)d_in[8];
    const float* b1 = (const float*)d_in[9];
    const float* W2 = (const float*)d_in[10];
    const float* b2 = (const float*)d_in[11];
    const float* Wr = (const float*)d_in[12];
    const float* br = (const float*)d_in[13];
    float* out = (float*)d_out;

    const int* erow = eidx;
    const int* ecol = eidx + EE;

    char* p = (char*)d_ws;
    auto alloc = [&](size_t bytes) {
        void* r = (void*)p;
        p += (bytes + 255) & ~(size_t)255;
        return r;
    };
    int* col_ptr = (int*)alloc((NN + 1) * sizeof(int));
    int* csr_src = (int*)alloc(EE * sizeof(int));
    int* cnt = (int*)alloc(NN * sizeof(int));
    int* cursor = (int*)alloc(NN * sizeof(int));
    int* chunk_sum = (int*)alloc(128 * sizeof(int));
    int* chunk_off = (int*)alloc(128 * sizeof(int));
    float* alpha = (float*)alloc(EE * sizeof(float));
    float* dinv1 = (float*)alloc(NN * sizeof(float));
    float* dinv2 = (float*)alloc(NN * sizeof(float));
    float* a_s = (float*)alloc(NN * sizeof(float));
    float* a_d = (float*)alloc(NN * sizeof(float));
    float* vs = (float*)alloc(HH * sizeof(float));
    float* vd = (float*)alloc(HH * sizeof(float));
    u16* bufA = (u16*)alloc((size_t)NN * HH * sizeof(u16));      // bf16 xw (gather source)
    float* bufB = (float*)alloc((size_t)NN * HH * sizeof(float)); // fp32 activations

    hipMemsetAsync(cnt, 0, NN * sizeof(int), stream);
    hipMemsetAsync(cursor, 0, NN * sizeof(int), stream);

    count_k<<<(EE + 255) / 256, 256, 0, stream>>>(ecol, cnt);
    dinv1_k<<<(NN + 255) / 256, 256, 0, stream>>>(cnt, dinv1);
    chunksum_k<<<NCHUNK, 256, 0, stream>>>(cnt, chunk_sum);
    chunkoff_k<<<1, 64, 0, stream>>>(chunk_sum, chunk_off, col_ptr);
    colptr_k<<<NCHUNK, 256, 0, stream>>>(cnt, chunk_off, col_ptr);
    fill_k<<<(EE + 255) / 256, 256, 0, stream>>>(erow, ecol, col_ptr, cursor, csr_src);
    gemv_vsvd_k<<<1, 128, 0, stream>>>(Wg, att_src, att_dst, vs, vd);

    dim3 g1((NN + 127) / 128, HH / 64);
    dim3 gr((NN + 127) / 128, FF / 64);
    int aggGrid = (NN + 3) / 4;

    // layer 1: bufA = bf16(x @ W0) ; bufB = x1 = relu(agg(bufA)) ; fused a_s/a_d
    gemm_k<FF, HH, true><<<g1, 256, 0, stream>>>(x, W0, nullptr, bufA, NN);
    aggregate_k<1><<<aggGrid, 256, 0, stream>>>(bufA, col_ptr, csr_src, nullptr, dinv1, b0, bufB,
                                                vs, vd, a_s, a_d);
    // attention coefficients
    attn_k<<<(NN + 255) / 256, 256, 0, stream>>>(col_ptr, csr_src, a_s, a_d, alpha, dinv2);
    // layer 2
    gemm_k<HH, HH, true><<<g1, 256, 0, stream>>>(bufB, W1, nullptr, bufA, NN);
    aggregate_k<2><<<aggGrid, 256, 0, stream>>>(bufA, col_ptr, csr_src, alpha, dinv2, b1, bufB,
                                                nullptr, nullptr, nullptr, nullptr);
    // layer 3
    gemm_k<HH, HH, true><<<g1, 256, 0, stream>>>(bufB, W2, nullptr, bufA, NN);
    aggregate_k<2><<<aggGrid, 256, 0, stream>>>(bufA, col_ptr, csr_src, alpha, dinv2, b2, bufB,
                                                nullptr, nullptr, nullptr, nullptr);
    // readout: out = x3 @ Wr + br  (output layout == (G,L,F) flattened)
    gemm_k<HH, FF, false><<<gr, 256, 0, stream>>>(bufB, Wr, br, out, NN);
}

// Round 4
// 339.878 us; speedup vs baseline: 1.4816x; 1.2581x over previous
//
#include <hip/hip_runtime.h>
#include <hip/hip_bf16.h>
#include <math.h>

#define NN 100000
#define EE 600000
#define FF 64
#define HH 128
#define CHUNK 1024
#define NCHUNK ((NN + CHUNK - 1) / CHUNK)   // 98
#define NCHUNKS_M (NN / 16)                 // 6250 (exact)

typedef unsigned short u16;
typedef __attribute__((ext_vector_type(8))) short bf16x8;
typedef __attribute__((ext_vector_type(4))) float f32x4;

__device__ __forceinline__ u16 f2bf(float f) {
    __hip_bfloat16 h = __float2bfloat16(f);
    return *(u16*)&h;
}
__device__ __forceinline__ float bf2f(u16 u) {
    unsigned int t = ((unsigned int)u) << 16;
    return *(float*)&t;
}

// ---------------- CSR build ----------------

__global__ void count_k(const int* __restrict__ col, int* __restrict__ cnt) {
    int e = blockIdx.x * 256 + threadIdx.x;
    if (e < EE) atomicAdd(&cnt[col[e]], 1);
}

__global__ void dinv1_k(const int* __restrict__ cnt, float* __restrict__ dinv1) {
    int c = blockIdx.x * 256 + threadIdx.x;
    if (c < NN) dinv1[c] = rsqrtf((float)cnt[c] + 1.0f);
}

__global__ void chunksum_k(const int* __restrict__ cnt, int* __restrict__ chunk_sum) {
    int b = blockIdx.x, t = threadIdx.x;
    int base = b * CHUNK + t * 4;
    int s = 0;
    #pragma unroll
    for (int i = 0; i < 4; i++) { int idx = base + i; if (idx < NN) s += cnt[idx]; }
    __shared__ int sm[4];
    for (int d = 32; d > 0; d >>= 1) s += __shfl_down(s, d);
    if ((t & 63) == 0) sm[t >> 6] = s;
    __syncthreads();
    if (t == 0) chunk_sum[b] = sm[0] + sm[1] + sm[2] + sm[3];
}

__global__ void chunkoff_k(const int* __restrict__ chunk_sum, int* __restrict__ chunk_off,
                           int* __restrict__ col_ptr) {
    if (threadIdx.x == 0) {
        int run = 0;
        for (int i = 0; i < NCHUNK; i++) { chunk_off[i] = run; run += chunk_sum[i]; }
        col_ptr[NN] = run;   // == EE
    }
}

__global__ void colptr_k(const int* __restrict__ cnt, const int* __restrict__ chunk_off,
                         int* __restrict__ col_ptr) {
    int b = blockIdx.x, t = threadIdx.x;
    int base = b * CHUNK + t * 4;
    int c[4]; int tot = 0;
    #pragma unroll
    for (int i = 0; i < 4; i++) { int idx = base + i; c[i] = (idx < NN) ? cnt[idx] : 0; tot += c[i]; }
    __shared__ int s[256];
    s[t] = tot;
    __syncthreads();
    for (int d = 1; d < 256; d <<= 1) {
        int v = (t >= d) ? s[t - d] : 0;
        __syncthreads();
        s[t] += v;
        __syncthreads();
    }
    int excl = s[t] - tot;
    int off = chunk_off[b] + excl;
    int pre = 0;
    #pragma unroll
    for (int i = 0; i < 4; i++) {
        int idx = base + i;
        if (idx < NN) col_ptr[idx] = off + pre;
        pre += c[i];
    }
}

__global__ void fill_k(const int* __restrict__ row, const int* __restrict__ col,
                       const int* __restrict__ col_ptr, int* __restrict__ cursor,
                       int* __restrict__ csr_src) {
    int e = blockIdx.x * 256 + threadIdx.x;
    if (e < EE) {
        int c = col[e];
        int slot = col_ptr[c] + atomicAdd(&cursor[c], 1);
        csr_src[slot] = row[e];
    }
}

// ---------------- tiny GEMV: vs = Wg @ att_src, vd = Wg @ att_dst ----------------

__global__ void gemv_vsvd_k(const float* __restrict__ Wg, const float* __restrict__ att_src,
                            const float* __restrict__ att_dst, float* __restrict__ vs,
                            float* __restrict__ vd) {
    int i = threadIdx.x;
    if (i < HH) {
        float s1 = 0.f, s2 = 0.f;
        for (int j = 0; j < HH; j++) {
            float w = Wg[i * HH + j];
            s1 += w * att_src[j];
            s2 += w * att_dst[j];
        }
        vs[i] = s1;
        vd[i] = s2;
    }
}

// ---------------- weight prep: Wt[n][k] = bf16(W[k][n]) for all four weights ----------------

__global__ void prep_wt_k(const float* __restrict__ W0, const float* __restrict__ W1,
                          const float* __restrict__ W2, const float* __restrict__ Wr,
                          u16* __restrict__ Wt0, u16* __restrict__ Wt1,
                          u16* __restrict__ Wt2, u16* __restrict__ Wtr) {
    int i = blockIdx.x * 256 + threadIdx.x;
    if (i < 8192) {                 // Wt0: [128][64] from W0[64][128]
        int n = i >> 6, k = i & 63;
        Wt0[i] = f2bf(W0[k * 128 + n]);
        return;
    }
    i -= 8192;
    if (i < 16384) {                // Wt1: [128][128]
        int n = i >> 7, k = i & 127;
        Wt1[i] = f2bf(W1[k * 128 + n]);
        return;
    }
    i -= 16384;
    if (i < 16384) {                // Wt2: [128][128]
        int n = i >> 7, k = i & 127;
        Wt2[i] = f2bf(W2[k * 128 + n]);
        return;
    }
    i -= 16384;
    if (i < 8192) {                 // Wtr: [64][128] from Wr[128][64]
        int n = i >> 7, k = i & 127;
        Wtr[i] = f2bf(Wr[k * 64 + n]);
    }
}

// ---------------- MFMA GEMM: C[M x N] = A[M x K] @ W[K x N] ----------------
// Wt is W transposed, bf16: Wt[n][k]. Each wave owns 16-row chunks (grid-stride).
// mfma_f32_16x16x32_bf16 with A-operand = Wt fragments, B-operand = activation rows:
//   D[i][j] = sum_k Wt[n0+i][k] * Act[m0+j][k] = C[m0+j][n0+i]
// Lane l: j = l&15 (output row), i = (l>>4)*4 + reg (output col) -> ushort4/float4 store.

template <int K, int N, bool AF32, bool OUTF32>
__global__ __launch_bounds__(256) void mfma_gemm_k(const void* __restrict__ A_,
                                                   const u16* __restrict__ Wt,
                                                   const float* __restrict__ bias,
                                                   void* __restrict__ C_) {
    constexpr int KK = K / 32;   // mfma k-steps
    constexpr int NT = N / 16;   // n-tiles
    int lane = threadIdx.x & 63;
    int l15 = lane & 15, l4 = lane >> 4;
    int wg = blockIdx.x * 4 + (threadIdx.x >> 6);
    int nwaves = gridDim.x * 4;

    // weight fragments: resident in registers for the whole kernel
    bf16x8 a_frag[KK][NT];
    #pragma unroll
    for (int kk = 0; kk < KK; kk++)
        #pragma unroll
        for (int nt = 0; nt < NT; nt++)
            a_frag[kk][nt] = *(const bf16x8*)&Wt[(size_t)(nt * 16 + l15) * K + kk * 32 + l4 * 8];

    f32x4 bias_f[NT];
    if (OUTF32) {
        #pragma unroll
        for (int nt = 0; nt < NT; nt++)
            bias_f[nt] = *(const f32x4*)&bias[nt * 16 + l4 * 4];
    }

    const float* Af = (const float*)A_;
    const u16* Ab = (const u16*)A_;
    float* Cf = (float*)C_;
    u16* Cb = (u16*)C_;

    for (int ch = wg; ch < NCHUNKS_M; ch += nwaves) {
        int row = ch * 16 + l15;
        bf16x8 b_frag[KK];
        #pragma unroll
        for (int kk = 0; kk < KK; kk++) {
            if (AF32) {
                float4 v0 = *(const float4*)&Af[(size_t)row * K + kk * 32 + l4 * 8];
                float4 v1 = *(const float4*)&Af[(size_t)row * K + kk * 32 + l4 * 8 + 4];
                bf16x8 b;
                b[0] = (short)f2bf(v0.x); b[1] = (short)f2bf(v0.y);
                b[2] = (short)f2bf(v0.z); b[3] = (short)f2bf(v0.w);
                b[4] = (short)f2bf(v1.x); b[5] = (short)f2bf(v1.y);
                b[6] = (short)f2bf(v1.z); b[7] = (short)f2bf(v1.w);
                b_frag[kk] = b;
            } else {
                b_frag[kk] = *(const bf16x8*)&Ab[(size_t)row * K + kk * 32 + l4 * 8];
            }
        }
        f32x4 acc[NT] = {};
        #pragma unroll
        for (int kk = 0; kk < KK; kk++)
            #pragma unroll
            for (int nt = 0; nt < NT; nt++)
                acc[nt] = __builtin_amdgcn_mfma_f32_16x16x32_bf16(a_frag[kk][nt], b_frag[kk],
                                                                  acc[nt], 0, 0, 0);
        #pragma unroll
        for (int nt = 0; nt < NT; nt++) {
            int col = nt * 16 + l4 * 4;
            if (OUTF32) {
                float4 o;
                o.x = acc[nt][0] + bias_f[nt][0];
                o.y = acc[nt][1] + bias_f[nt][1];
                o.z = acc[nt][2] + bias_f[nt][2];
                o.w = acc[nt][3] + bias_f[nt][3];
                *(float4*)&Cf[(size_t)row * N + col] = o;
            } else {
                ushort4 o;
                o.x = f2bf(acc[nt][0]);
                o.y = f2bf(acc[nt][1]);
                o.z = f2bf(acc[nt][2]);
                o.w = f2bf(acc[nt][3]);
                *(ushort4*)&Cb[(size_t)row * N + col] = o;
            }
        }
    }
}

// ---------------- GCN aggregation: wave per node, bf16 in/out, 4 gathers in flight ----------------

template <int LAYER>
__global__ __launch_bounds__(256) void aggregate_k(
    const u16* __restrict__ xw, const int* __restrict__ col_ptr, const int* __restrict__ csr_src,
    const float* __restrict__ alpha, const float* __restrict__ dinv, const float* __restrict__ bias,
    u16* __restrict__ xout, const float* __restrict__ vs, const float* __restrict__ vd,
    float* __restrict__ a_s, float* __restrict__ a_d) {
    int wid = threadIdx.x >> 6, lane = threadIdx.x & 63;
    int c = blockIdx.x * 4 + wid;
    if (c >= NN) return;
    int half = lane >> 5;
    int ch = (lane & 31) << 2;     // channel base: 0,4,...,124
    int beg = col_ptr[c], end = col_ptr[c + 1];
    float dc = dinv[c];
    float4 acc = make_float4(0.f, 0.f, 0.f, 0.f);

    int pA = beg + half;
    int pB = pA + 2;
    int rA = 0, rB = 0; float wA = 0.f, wB = 0.f;
    if (pA < end) {
        rA = csr_src[pA];
        wA = (LAYER == 1) ? dinv[rA] * dc : dinv[rA] * alpha[pA] * dc;
    }
    if (pB < end) {
        rB = csr_src[pB];
        wB = (LAYER == 1) ? dinv[rB] * dc : dinv[rB] * alpha[pB] * dc;
    }
    while (pA < end) {
        bool hb = pB < end;
        ushort4 vA = *(const ushort4*)&xw[(size_t)rA * HH + ch];
        ushort4 vB;
        if (hb) vB = *(const ushort4*)&xw[(size_t)rB * HH + ch];
        int pA2 = pA + 4, pB2 = pB + 4;
        int rA2 = 0, rB2 = 0; float wA2 = 0.f, wB2 = 0.f;
        if (pA2 < end) {
            rA2 = csr_src[pA2];
            wA2 = (LAYER == 1) ? dinv[rA2] * dc : dinv[rA2] * alpha[pA2] * dc;
        }
        if (pB2 < end) {
            rB2 = csr_src[pB2];
            wB2 = (LAYER == 1) ? dinv[rB2] * dc : dinv[rB2] * alpha[pB2] * dc;
        }
        acc.x += bf2f(vA.x) * wA;
        acc.y += bf2f(vA.y) * wA;
        acc.z += bf2f(vA.z) * wA;
        acc.w += bf2f(vA.w) * wA;
        if (hb) {
            acc.x += bf2f(vB.x) * wB;
            acc.y += bf2f(vB.y) * wB;
            acc.z += bf2f(vB.z) * wB;
            acc.w += bf2f(vB.w) * wB;
        }
        pA = pA2; pB = pB2; rA = rA2; rB = rB2; wA = wA2; wB = wB2;
    }
    // combine even/odd halves
    acc.x += __shfl(acc.x, lane ^ 32);
    acc.y += __shfl(acc.y, lane ^ 32);
    acc.z += __shfl(acc.z, lane ^ 32);
    acc.w += __shfl(acc.w, lane ^ 32);

    if (half == 0) {
        // self loop (weight dc*dc) + bias + relu
        ushort4 v = *(const ushort4*)&xw[(size_t)c * HH + ch];
        float ws = dc * dc;
        float4 b4 = *(const float4*)&bias[ch];
        acc.x = fmaxf(fmaf(bf2f(v.x), ws, acc.x) + b4.x, 0.f);
        acc.y = fmaxf(fmaf(bf2f(v.y), ws, acc.y) + b4.y, 0.f);
        acc.z = fmaxf(fmaf(bf2f(v.z), ws, acc.z) + b4.z, 0.f);
        acc.w = fmaxf(fmaf(bf2f(v.w), ws, acc.w) + b4.w, 0.f);
        ushort4 o;
        o.x = f2bf(acc.x); o.y = f2bf(acc.y); o.z = f2bf(acc.z); o.w = f2bf(acc.w);
        *(ushort4*)&xout[(size_t)c * HH + ch] = o;
        if (LAYER == 1) {
            float4 s4 = *(const float4*)&vs[ch];
            float4 d4 = *(const float4*)&vd[ch];
            float s1 = acc.x * s4.x + acc.y * s4.y + acc.z * s4.z + acc.w * s4.w;
            float s2 = acc.x * d4.x + acc.y * d4.y + acc.z * d4.z + acc.w * d4.w;
            for (int d = 16; d > 0; d >>= 1) {
                s1 += __shfl_down(s1, d);
                s2 += __shfl_down(s2, d);
            }
            if (lane == 0) {
                a_s[c] = s1;
                a_d[c] = s2;
            }
        }
    }
}

// ---------------- attention: per-node softmax over incoming edges + self ----------------

__global__ void attn_k(const int* __restrict__ col_ptr, const int* __restrict__ csr_src,
                       const float* __restrict__ a_s, const float* __restrict__ a_d,
                       float* __restrict__ alpha, float* __restrict__ dinv2) {
    int c = blockIdx.x * 256 + threadIdx.x;
    if (c >= NN) return;
    int beg = col_ptr[c], end = col_ptr[c + 1];
    float ad = a_d[c];
    float es = a_s[c] + ad;
    es = (es > 0.f) ? es : 0.2f * es;
    float m = es;
    for (int p = beg; p < end; p++) {
        float e = a_s[csr_src[p]] + ad;
        e = (e > 0.f) ? e : 0.2f * e;
        alpha[p] = e;
        m = fmaxf(m, e);
    }
    float exs = expf(es - m);
    float s = exs;
    for (int p = beg; p < end; p++) {
        float ex = expf(alpha[p] - m);
        alpha[p] = ex;
        s += ex;
    }
    float inv = 1.f / s;
    for (int p = beg; p < end; p++) alpha[p] *= inv;
    dinv2[c] = rsqrtf(2.f - exs * inv);
}

// ---------------- launch ----------------

extern "C" void kernel_launch(void* const* d_in, const int* in_sizes, int n_in,
                              void* d_out, int out_size, void* d_ws, size_t ws_size,
                              hipStream_t stream) {
    const float* x = (const float*)d_in[0];
    const int* eidx = (const int*)d_in[1];     // [2][E]: row, col
    const float* W0 = (const float*)d_in[3];
    const float* Wg = (const float*)d_in[5];
    const float* att_src = (const float*)d_in[6];
    const float* att_dst = (const float*)d_in[7];
    const float* b0 = (const float*)d_in[4];
    const float* W1 = (const float*)d_in[8];
    const float* b1 = (const float*)d_in[9];
    const float* W2 = (const float*)d_in[10];
    const float* b2 = (const float*)d_in[11];
    const float* Wr = (const float*)d_in[12];
    const float* br = (const float*)d_in[13];
    float* out = (float*)d_out;

    const int* erow = eidx;
    const int* ecol = eidx + EE;

    char* p = (char*)d_ws;
    auto alloc = [&](size_t bytes) {
        void* r = (void*)p;
        p += (bytes + 255) & ~(size_t)255;
        return r;
    };
    int* col_ptr = (int*)alloc((NN + 1) * sizeof(int));
    int* csr_src = (int*)alloc(EE * sizeof(int));
    int* cnt = (int*)alloc(NN * sizeof(int));
    int* cursor = (int*)alloc(NN * sizeof(int));
    int* chunk_sum = (int*)alloc(128 * sizeof(int));
    int* chunk_off = (int*)alloc(128 * sizeof(int));
    float* alpha = (float*)alloc(EE * sizeof(float));
    float* dinv1 = (float*)alloc(NN * sizeof(float));
    float* dinv2 = (float*)alloc(NN * sizeof(float));
    float* a_s = (float*)alloc(NN * sizeof(float));
    float* a_d = (float*)alloc(NN * sizeof(float));
    float* vs = (float*)alloc(HH * sizeof(float));
    float* vd = (float*)alloc(HH * sizeof(float));
    u16* Wt0 = (u16*)alloc(8192 * sizeof(u16));    // [128][64]
    u16* Wt1 = (u16*)alloc(16384 * sizeof(u16));   // [128][128]
    u16* Wt2 = (u16*)alloc(16384 * sizeof(u16));   // [128][128]
    u16* Wtr = (u16*)alloc(8192 * sizeof(u16));    // [64][128]
    u16* bufA = (u16*)alloc((size_t)NN * HH * sizeof(u16));  // bf16 xw (gather source)
    u16* bufB = (u16*)alloc((size_t)NN * HH * sizeof(u16));  // bf16 activations

    hipMemsetAsync(cnt, 0, NN * sizeof(int), stream);
    hipMemsetAsync(cursor, 0, NN * sizeof(int), stream);

    count_k<<<(EE + 255) / 256, 256, 0, stream>>>(ecol, cnt);
    dinv1_k<<<(NN + 255) / 256, 256, 0, stream>>>(cnt, dinv1);
    chunksum_k<<<NCHUNK, 256, 0, stream>>>(cnt, chunk_sum);
    chunkoff_k<<<1, 64, 0, stream>>>(chunk_sum, chunk_off, col_ptr);
    colptr_k<<<NCHUNK, 256, 0, stream>>>(cnt, chunk_off, col_ptr);
    fill_k<<<(EE + 255) / 256, 256, 0, stream>>>(erow, ecol, col_ptr, cursor, csr_src);
    gemv_vsvd_k<<<1, 128, 0, stream>>>(Wg, att_src, att_dst, vs, vd);
    prep_wt_k<<<192, 256, 0, stream>>>(W0, W1, W2, Wr, Wt0, Wt1, Wt2, Wtr);

    int aggGrid = (NN + 3) / 4;
    const int GG = 512;   // gemm grid (blocks of 4 waves)

    // layer 1: bufA = bf16(x @ W0) ; bufB = x1 ; fused a_s/a_d
    mfma_gemm_k<FF, HH, true, false><<<GG, 256, 0, stream>>>(x, Wt0, nullptr, bufA);
    aggregate_k<1><<<aggGrid, 256, 0, stream>>>(bufA, col_ptr, csr_src, nullptr, dinv1, b0, bufB,
                                                vs, vd, a_s, a_d);
    attn_k<<<(NN + 255) / 256, 256, 0, stream>>>(col_ptr, csr_src, a_s, a_d, alpha, dinv2);
    // layer 2
    mfma_gemm_k<HH, HH, false, false><<<GG, 256, 0, stream>>>(bufB, Wt1, nullptr, bufA);
    aggregate_k<2><<<aggGrid, 256, 0, stream>>>(bufA, col_ptr, csr_src, alpha, dinv2, b1, bufB,
                                                nullptr, nullptr, nullptr, nullptr);
    // layer 3
    mfma_gemm_k<HH, HH, false, false><<<GG, 256, 0, stream>>>(bufB, Wt2, nullptr, bufA);
    aggregate_k<2><<<aggGrid, 256, 0, stream>>>(bufA, col_ptr, csr_src, alpha, dinv2, b2, bufB,
                                                nullptr, nullptr, nullptr, nullptr);
    // readout: out = x3 @ Wr + br (fp32 out)
    mfma_gemm_k<HH, FF, false, true><<<GG, 256, 0, stream>>>(bufB, Wtr, br, out);
}

// Round 5
// 279.330 us; speedup vs baseline: 1.8028x; 1.2168x over previous
//
#include <hip/hip_runtime.h>
#include <hip/hip_bf16.h>
#include <math.h>

#define NN 100000
#define EE 600000
#define FF 64
#define HH 128
#define CHUNK 1024
#define NCHUNK ((NN + CHUNK - 1) / CHUNK)   // 98
#define NCHUNKS_M (NN / 16)                 // 6250 (exact)

typedef unsigned short u16;
typedef __attribute__((ext_vector_type(8))) short bf16x8;
typedef __attribute__((ext_vector_type(4))) float f32x4;

__device__ __forceinline__ u16 f2bf(float f) {
    __hip_bfloat16 h = __float2bfloat16(f);
    return *(u16*)&h;
}
__device__ __forceinline__ float bf2f(u16 u) {
    unsigned int t = ((unsigned int)u) << 16;
    return *(float*)&t;
}

// ---------------- CSR build ----------------

__global__ void count_k(const int* __restrict__ col, int* __restrict__ cnt) {
    int e = blockIdx.x * 256 + threadIdx.x;
    if (e < EE) atomicAdd(&cnt[col[e]], 1);
}

__global__ void dinv1_k(const int* __restrict__ cnt, float* __restrict__ dinv1) {
    int c = blockIdx.x * 256 + threadIdx.x;
    if (c < NN) dinv1[c] = rsqrtf((float)cnt[c] + 1.0f);
}

__global__ void chunksum_k(const int* __restrict__ cnt, int* __restrict__ chunk_sum) {
    int b = blockIdx.x, t = threadIdx.x;
    int base = b * CHUNK + t * 4;
    int s = 0;
    #pragma unroll
    for (int i = 0; i < 4; i++) { int idx = base + i; if (idx < NN) s += cnt[idx]; }
    __shared__ int sm[4];
    for (int d = 32; d > 0; d >>= 1) s += __shfl_down(s, d);
    if ((t & 63) == 0) sm[t >> 6] = s;
    __syncthreads();
    if (t == 0) chunk_sum[b] = sm[0] + sm[1] + sm[2] + sm[3];
}

__global__ void chunkoff_k(const int* __restrict__ chunk_sum, int* __restrict__ chunk_off,
                           int* __restrict__ col_ptr) {
    if (threadIdx.x == 0) {
        int run = 0;
        for (int i = 0; i < NCHUNK; i++) { chunk_off[i] = run; run += chunk_sum[i]; }
        col_ptr[NN] = run;   // == EE
    }
}

__global__ void colptr_k(const int* __restrict__ cnt, const int* __restrict__ chunk_off,
                         int* __restrict__ col_ptr) {
    int b = blockIdx.x, t = threadIdx.x;
    int base = b * CHUNK + t * 4;
    int c[4]; int tot = 0;
    #pragma unroll
    for (int i = 0; i < 4; i++) { int idx = base + i; c[i] = (idx < NN) ? cnt[idx] : 0; tot += c[i]; }
    __shared__ int s[256];
    s[t] = tot;
    __syncthreads();
    for (int d = 1; d < 256; d <<= 1) {
        int v = (t >= d) ? s[t - d] : 0;
        __syncthreads();
        s[t] += v;
        __syncthreads();
    }
    int excl = s[t] - tot;
    int off = chunk_off[b] + excl;
    int pre = 0;
    #pragma unroll
    for (int i = 0; i < 4; i++) {
        int idx = base + i;
        if (idx < NN) col_ptr[idx] = off + pre;
        pre += c[i];
    }
}

// fill CSR; also precompute layer-1 edge weight dinv1[r]*dinv1[c]
__global__ void fill_k(const int* __restrict__ row, const int* __restrict__ col,
                       const int* __restrict__ col_ptr, int* __restrict__ cursor,
                       const float* __restrict__ dinv1, int* __restrict__ csr_src,
                       float* __restrict__ csr_w) {
    int e = blockIdx.x * 256 + threadIdx.x;
    if (e < EE) {
        int r = row[e], c = col[e];
        int slot = col_ptr[c] + atomicAdd(&cursor[c], 1);
        csr_src[slot] = r;
        csr_w[slot] = dinv1[r] * dinv1[c];
    }
}

// ---------------- x -> bf16 cast ----------------

__global__ void cast_k(const float* __restrict__ x, u16* __restrict__ xb) {
    int i = blockIdx.x * 256 + threadIdx.x;
    if (i < NN * FF / 4) {
        float4 v = ((const float4*)x)[i];
        ushort4 o;
        o.x = f2bf(v.x); o.y = f2bf(v.y); o.z = f2bf(v.z); o.w = f2bf(v.w);
        ((ushort4*)xb)[i] = o;
    }
}

// ---------------- tiny GEMV: vs = Wg @ att_src, vd = Wg @ att_dst ----------------

__global__ void gemv_vsvd_k(const float* __restrict__ Wg, const float* __restrict__ att_src,
                            const float* __restrict__ att_dst, float* __restrict__ vs,
                            float* __restrict__ vd) {
    int i = threadIdx.x;
    if (i < HH) {
        float s1 = 0.f, s2 = 0.f;
        for (int j = 0; j < HH; j++) {
            float w = Wg[i * HH + j];
            s1 += w * att_src[j];
            s2 += w * att_dst[j];
        }
        vs[i] = s1;
        vd[i] = s2;
    }
}

// ---------------- weight prep: Wt[n][k] = bf16(W[k][n]) ----------------

__global__ void prep_wt_k(const float* __restrict__ W0, const float* __restrict__ W1,
                          const float* __restrict__ W2, const float* __restrict__ Wr,
                          u16* __restrict__ Wt0, u16* __restrict__ Wt1,
                          u16* __restrict__ Wt2, u16* __restrict__ Wtr) {
    int i = blockIdx.x * 256 + threadIdx.x;
    if (i < 8192) {                 // Wt0: [128][64] from W0[64][128]
        int n = i >> 6, k = i & 63;
        Wt0[i] = f2bf(W0[k * 128 + n]);
        return;
    }
    i -= 8192;
    if (i < 16384) {                // Wt1: [128][128]
        int n = i >> 7, k = i & 127;
        Wt1[i] = f2bf(W1[k * 128 + n]);
        return;
    }
    i -= 16384;
    if (i < 16384) {                // Wt2: [128][128]
        int n = i >> 7, k = i & 127;
        Wt2[i] = f2bf(W2[k * 128 + n]);
        return;
    }
    i -= 16384;
    if (i < 8192) {                 // Wtr: [64][128] from Wr[128][64]
        int n = i >> 7, k = i & 127;
        Wtr[i] = f2bf(Wr[k * 64 + n]);
    }
}

// ---------------- layer-1 aggregate in x-space: 64 ch, quarter-wave per edge ----------------

__global__ __launch_bounds__(256) void aggx_k(
    const u16* __restrict__ xb, const int* __restrict__ col_ptr, const int* __restrict__ csr_src,
    const float* __restrict__ csr_w, const float* __restrict__ dinv1, u16* __restrict__ xout) {
    int wid = threadIdx.x >> 6, lane = threadIdx.x & 63;
    int c = blockIdx.x * 4 + wid;
    if (c >= NN) return;
    int q = lane >> 4;           // quarter 0..3
    int ch = (lane & 15) << 2;   // channel base 0..60
    int beg = col_ptr[c], end = col_ptr[c + 1];
    float4 acc = make_float4(0.f, 0.f, 0.f, 0.f);

    int pA = beg + q, pB = pA + 4;
    int rA = 0, rB = 0; float wA = 0.f, wB = 0.f;
    if (pA < end) { rA = csr_src[pA]; wA = csr_w[pA]; }
    if (pB < end) { rB = csr_src[pB]; wB = csr_w[pB]; }
    while (pA < end) {
        bool hb = pB < end;
        ushort4 vA = *(const ushort4*)&xb[(size_t)rA * FF + ch];
        ushort4 vB;
        if (hb) vB = *(const ushort4*)&xb[(size_t)rB * FF + ch];
        int pA2 = pA + 8, pB2 = pB + 8;
        int rA2 = 0, rB2 = 0; float wA2 = 0.f, wB2 = 0.f;
        if (pA2 < end) { rA2 = csr_src[pA2]; wA2 = csr_w[pA2]; }
        if (pB2 < end) { rB2 = csr_src[pB2]; wB2 = csr_w[pB2]; }
        acc.x += bf2f(vA.x) * wA;
        acc.y += bf2f(vA.y) * wA;
        acc.z += bf2f(vA.z) * wA;
        acc.w += bf2f(vA.w) * wA;
        if (hb) {
            acc.x += bf2f(vB.x) * wB;
            acc.y += bf2f(vB.y) * wB;
            acc.z += bf2f(vB.z) * wB;
            acc.w += bf2f(vB.w) * wB;
        }
        pA = pA2; pB = pB2; rA = rA2; rB = rB2; wA = wA2; wB = wB2;
    }
    // combine quarters
    acc.x += __shfl_xor(acc.x, 16); acc.y += __shfl_xor(acc.y, 16);
    acc.z += __shfl_xor(acc.z, 16); acc.w += __shfl_xor(acc.w, 16);
    acc.x += __shfl_xor(acc.x, 32); acc.y += __shfl_xor(acc.y, 32);
    acc.z += __shfl_xor(acc.z, 32); acc.w += __shfl_xor(acc.w, 32);

    if (q == 0) {
        ushort4 v = *(const ushort4*)&xb[(size_t)c * FF + ch];
        float dc = dinv1[c];
        float ws = dc * dc;
        acc.x = fmaf(bf2f(v.x), ws, acc.x);
        acc.y = fmaf(bf2f(v.y), ws, acc.y);
        acc.z = fmaf(bf2f(v.z), ws, acc.z);
        acc.w = fmaf(bf2f(v.w), ws, acc.w);
        ushort4 o;
        o.x = f2bf(acc.x); o.y = f2bf(acc.y); o.z = f2bf(acc.z); o.w = f2bf(acc.w);
        *(ushort4*)&xout[(size_t)c * FF + ch] = o;
    }
}

// ---------------- GEMM1: x1 = relu(xagg @ W0 + b0), fused a_s/a_d ----------------

__global__ __launch_bounds__(256) void gemm1_k(const u16* __restrict__ A, const u16* __restrict__ Wt,
                                               const float* __restrict__ bias,
                                               const float* __restrict__ vs, const float* __restrict__ vd,
                                               u16* __restrict__ C, float* __restrict__ a_s,
                                               float* __restrict__ a_d) {
    constexpr int K = FF, N = HH, KK = K / 32, NT = N / 16;
    int lane = threadIdx.x & 63;
    int l15 = lane & 15, l4 = lane >> 4;
    int wg = blockIdx.x * 4 + (threadIdx.x >> 6);
    int nwaves = gridDim.x * 4;

    bf16x8 a_frag[KK][NT];
    #pragma unroll
    for (int kk = 0; kk < KK; kk++)
        #pragma unroll
        for (int nt = 0; nt < NT; nt++)
            a_frag[kk][nt] = *(const bf16x8*)&Wt[(size_t)(nt * 16 + l15) * K + kk * 32 + l4 * 8];
    f32x4 bias_f[NT], vs_f[NT], vd_f[NT];
    #pragma unroll
    for (int nt = 0; nt < NT; nt++) {
        bias_f[nt] = *(const f32x4*)&bias[nt * 16 + l4 * 4];
        vs_f[nt] = *(const f32x4*)&vs[nt * 16 + l4 * 4];
        vd_f[nt] = *(const f32x4*)&vd[nt * 16 + l4 * 4];
    }

    for (int ch = wg; ch < NCHUNKS_M; ch += nwaves) {
        int row = ch * 16 + l15;
        bf16x8 b_frag[KK];
        #pragma unroll
        for (int kk = 0; kk < KK; kk++)
            b_frag[kk] = *(const bf16x8*)&A[(size_t)row * K + kk * 32 + l4 * 8];
        f32x4 acc[NT] = {};
        #pragma unroll
        for (int kk = 0; kk < KK; kk++)
            #pragma unroll
            for (int nt = 0; nt < NT; nt++)
                acc[nt] = __builtin_amdgcn_mfma_f32_16x16x32_bf16(a_frag[kk][nt], b_frag[kk],
                                                                  acc[nt], 0, 0, 0);
        float s1 = 0.f, s2 = 0.f;
        #pragma unroll
        for (int nt = 0; nt < NT; nt++) {
            float o0 = fmaxf(acc[nt][0] + bias_f[nt][0], 0.f);
            float o1 = fmaxf(acc[nt][1] + bias_f[nt][1], 0.f);
            float o2 = fmaxf(acc[nt][2] + bias_f[nt][2], 0.f);
            float o3 = fmaxf(acc[nt][3] + bias_f[nt][3], 0.f);
            ushort4 o;
            o.x = f2bf(o0); o.y = f2bf(o1); o.z = f2bf(o2); o.w = f2bf(o3);
            *(ushort4*)&C[(size_t)row * N + nt * 16 + l4 * 4] = o;
            s1 += o0 * vs_f[nt][0] + o1 * vs_f[nt][1] + o2 * vs_f[nt][2] + o3 * vs_f[nt][3];
            s2 += o0 * vd_f[nt][0] + o1 * vd_f[nt][1] + o2 * vd_f[nt][2] + o3 * vd_f[nt][3];
        }
        s1 += __shfl_xor(s1, 16); s1 += __shfl_xor(s1, 32);
        s2 += __shfl_xor(s2, 16); s2 += __shfl_xor(s2, 32);
        if (l4 == 0) {
            a_s[row] = s1;
            a_d[row] = s2;
        }
    }
}

// ---------------- MFMA GEMM (layers 2/3 + readout) ----------------

template <int K, int N, bool OUTF32>
__global__ __launch_bounds__(256) void mfma_gemm_k(const u16* __restrict__ A,
                                                   const u16* __restrict__ Wt,
                                                   const float* __restrict__ bias,
                                                   void* __restrict__ C_) {
    constexpr int KK = K / 32;
    constexpr int NT = N / 16;
    int lane = threadIdx.x & 63;
    int l15 = lane & 15, l4 = lane >> 4;
    int wg = blockIdx.x * 4 + (threadIdx.x >> 6);
    int nwaves = gridDim.x * 4;

    bf16x8 a_frag[KK][NT];
    #pragma unroll
    for (int kk = 0; kk < KK; kk++)
        #pragma unroll
        for (int nt = 0; nt < NT; nt++)
            a_frag[kk][nt] = *(const bf16x8*)&Wt[(size_t)(nt * 16 + l15) * K + kk * 32 + l4 * 8];

    f32x4 bias_f[NT];
    if (OUTF32) {
        #pragma unroll
        for (int nt = 0; nt < NT; nt++)
            bias_f[nt] = *(const f32x4*)&bias[nt * 16 + l4 * 4];
    }

    float* Cf = (float*)C_;
    u16* Cb = (u16*)C_;

    for (int ch = wg; ch < NCHUNKS_M; ch += nwaves) {
        int row = ch * 16 + l15;
        bf16x8 b_frag[KK];
        #pragma unroll
        for (int kk = 0; kk < KK; kk++)
            b_frag[kk] = *(const bf16x8*)&A[(size_t)row * K + kk * 32 + l4 * 8];
        f32x4 acc[NT] = {};
        #pragma unroll
        for (int kk = 0; kk < KK; kk++)
            #pragma unroll
            for (int nt = 0; nt < NT; nt++)
                acc[nt] = __builtin_amdgcn_mfma_f32_16x16x32_bf16(a_frag[kk][nt], b_frag[kk],
                                                                  acc[nt], 0, 0, 0);
        #pragma unroll
        for (int nt = 0; nt < NT; nt++) {
            int col = nt * 16 + l4 * 4;
            if (OUTF32) {
                float4 o;
                o.x = acc[nt][0] + bias_f[nt][0];
                o.y = acc[nt][1] + bias_f[nt][1];
                o.z = acc[nt][2] + bias_f[nt][2];
                o.w = acc[nt][3] + bias_f[nt][3];
                *(float4*)&Cf[(size_t)row * N + col] = o;
            } else {
                ushort4 o;
                o.x = f2bf(acc[nt][0]);
                o.y = f2bf(acc[nt][1]);
                o.z = f2bf(acc[nt][2]);
                o.w = f2bf(acc[nt][3]);
                *(ushort4*)&Cb[(size_t)row * N + col] = o;
            }
        }
    }
}

// ---------------- attention: 8 lanes per node, online softmax ----------------
// writes alpha[p] = softmax * dinv2[c]  (dinv2[r] applied by w2_k)

__global__ __launch_bounds__(256) void attn_k(const int* __restrict__ col_ptr,
                                              const int* __restrict__ csr_src,
                                              const float* __restrict__ a_s,
                                              const float* __restrict__ a_d,
                                              float* __restrict__ alpha,
                                              float* __restrict__ dinv2) {
    int lane = threadIdx.x & 63, wid = threadIdx.x >> 6;
    int grp = lane >> 3, idx = lane & 7;
    int c = blockIdx.x * 32 + wid * 8 + grp;
    if (c >= NN) return;
    int beg = col_ptr[c], end = col_ptr[c + 1];
    float ad = a_d[c];
    float es = a_s[c] + ad;
    es = (es > 0.f) ? es : 0.2f * es;
    float m = (idx == 0) ? es : -1e30f;
    float s = (idx == 0) ? 1.f : 0.f;
    for (int p = beg + idx; p < end; p += 8) {
        float e = a_s[csr_src[p]] + ad;
        e = (e > 0.f) ? e : 0.2f * e;
        alpha[p] = e;
        float mn = fmaxf(m, e);
        s = s * expf(m - mn) + expf(e - mn);
        m = mn;
    }
    #pragma unroll
    for (int d = 1; d < 8; d <<= 1) {
        float mo = __shfl_xor(m, d);
        float so = __shfl_xor(s, d);
        float mn = fmaxf(m, mo);
        s = s * expf(m - mn) + so * expf(mo - mn);
        m = mn;
    }
    float inv = 1.f / s;
    float aself = expf(es - m) * inv;
    float d2 = rsqrtf(2.f - aself);
    if (idx == 0) dinv2[c] = d2;
    float sc = inv * d2;
    for (int p = beg + idx; p < end; p += 8)
        alpha[p] = expf(alpha[p] - m) * sc;
}

// alpha[p] *= dinv2[src]   (completes w = dinv2[r]*alpha*dinv2[c])
__global__ void w2_k(const int* __restrict__ csr_src, const float* __restrict__ dinv2,
                     float* __restrict__ alpha) {
    int p = blockIdx.x * 256 + threadIdx.x;
    if (p < EE) alpha[p] *= dinv2[csr_src[p]];
}

// ---------------- layers 2/3 aggregate: 128 ch, half-wave x 3 streams ----------------

__global__ __launch_bounds__(256) void agg2_k(
    const u16* __restrict__ xw, const int* __restrict__ col_ptr, const int* __restrict__ csr_src,
    const float* __restrict__ w2, const float* __restrict__ dinv2, const float* __restrict__ bias,
    u16* __restrict__ xout) {
    int wid = threadIdx.x >> 6, lane = threadIdx.x & 63;
    int c = blockIdx.x * 4 + wid;
    if (c >= NN) return;
    int half = lane >> 5;
    int ch = (lane & 31) << 2;
    int beg = col_ptr[c], end = col_ptr[c + 1];
    float4 acc = make_float4(0.f, 0.f, 0.f, 0.f);

    int pA = beg + half, pB = pA + 2, pC = pA + 4;
    int rA = 0, rB = 0, rC = 0; float wA = 0.f, wB = 0.f, wC = 0.f;
    if (pA < end) { rA = csr_src[pA]; wA = w2[pA]; }
    if (pB < end) { rB = csr_src[pB]; wB = w2[pB]; }
    if (pC < end) { rC = csr_src[pC]; wC = w2[pC]; }
    while (pA < end) {
        bool hb = pB < end, hc = pC < end;
        ushort4 vA = *(const ushort4*)&xw[(size_t)rA * HH + ch];
        ushort4 vB, vC;
        if (hb) vB = *(const ushort4*)&xw[(size_t)rB * HH + ch];
        if (hc) vC = *(const ushort4*)&xw[(size_t)rC * HH + ch];
        int pA2 = pA + 6, pB2 = pB + 6, pC2 = pC + 6;
        int rA2 = 0, rB2 = 0, rC2 = 0; float wA2 = 0.f, wB2 = 0.f, wC2 = 0.f;
        if (pA2 < end) { rA2 = csr_src[pA2]; wA2 = w2[pA2]; }
        if (pB2 < end) { rB2 = csr_src[pB2]; wB2 = w2[pB2]; }
        if (pC2 < end) { rC2 = csr_src[pC2]; wC2 = w2[pC2]; }
        acc.x += bf2f(vA.x) * wA;
        acc.y += bf2f(vA.y) * wA;
        acc.z += bf2f(vA.z) * wA;
        acc.w += bf2f(vA.w) * wA;
        if (hb) {
            acc.x += bf2f(vB.x) * wB;
            acc.y += bf2f(vB.y) * wB;
            acc.z += bf2f(vB.z) * wB;
            acc.w += bf2f(vB.w) * wB;
        }
        if (hc) {
            acc.x += bf2f(vC.x) * wC;
            acc.y += bf2f(vC.y) * wC;
            acc.z += bf2f(vC.z) * wC;
            acc.w += bf2f(vC.w) * wC;
        }
        pA = pA2; pB = pB2; pC = pC2;
        rA = rA2; rB = rB2; rC = rC2;
        wA = wA2; wB = wB2; wC = wC2;
    }
    acc.x += __shfl_xor(acc.x, 32);
    acc.y += __shfl_xor(acc.y, 32);
    acc.z += __shfl_xor(acc.z, 32);
    acc.w += __shfl_xor(acc.w, 32);

    if (half == 0) {
        ushort4 v = *(const ushort4*)&xw[(size_t)c * HH + ch];
        float dc = dinv2[c];
        float ws = dc * dc;
        float4 b4 = *(const float4*)&bias[ch];
        acc.x = fmaxf(fmaf(bf2f(v.x), ws, acc.x) + b4.x, 0.f);
        acc.y = fmaxf(fmaf(bf2f(v.y), ws, acc.y) + b4.y, 0.f);
        acc.z = fmaxf(fmaf(bf2f(v.z), ws, acc.z) + b4.z, 0.f);
        acc.w = fmaxf(fmaf(bf2f(v.w), ws, acc.w) + b4.w, 0.f);
        ushort4 o;
        o.x = f2bf(acc.x); o.y = f2bf(acc.y); o.z = f2bf(acc.z); o.w = f2bf(acc.w);
        *(ushort4*)&xout[(size_t)c * HH + ch] = o;
    }
}

// ---------------- launch ----------------

extern "C" void kernel_launch(void* const* d_in, const int* in_sizes, int n_in,
                              void* d_out, int out_size, void* d_ws, size_t ws_size,
                              hipStream_t stream) {
    const float* x = (const float*)d_in[0];
    const int* eidx = (const int*)d_in[1];     // [2][E]: row, col
    const float* W0 = (const float*)d_in[3];
    const float* b0 = (const float*)d_in[4];
    const float* Wg = (const float*)d_in[5];
    const float* att_src = (const float*)d_in[6];
    const float* att_dst = (const float*)d_in[7];
    const float* W1 = (const float*)d_in[8];
    const float* b1 = (const float*)d_in[9];
    const float* W2 = (const float*)d_in[10];
    const float* b2 = (const float*)d_in[11];
    const float* Wr = (const float*)d_in[12];
    const float* br = (const float*)d_in[13];
    float* out = (float*)d_out;

    const int* erow = eidx;
    const int* ecol = eidx + EE;

    char* p = (char*)d_ws;
    auto alloc = [&](size_t bytes) {
        void* r = (void*)p;
        p += (bytes + 255) & ~(size_t)255;
        return r;
    };
    int* col_ptr = (int*)alloc((NN + 1) * sizeof(int));
    int* csr_src = (int*)alloc(EE * sizeof(int));
    float* csr_w = (float*)alloc(EE * sizeof(float));
    int* cnt = (int*)alloc(NN * sizeof(int));
    int* cursor = (int*)alloc(NN * sizeof(int));
    int* chunk_sum = (int*)alloc(128 * sizeof(int));
    int* chunk_off = (int*)alloc(128 * sizeof(int));
    float* alpha = (float*)alloc(EE * sizeof(float));
    float* dinv1 = (float*)alloc(NN * sizeof(float));
    float* dinv2 = (float*)alloc(NN * sizeof(float));
    float* a_s = (float*)alloc(NN * sizeof(float));
    float* a_d = (float*)alloc(NN * sizeof(float));
    float* vs = (float*)alloc(HH * sizeof(float));
    float* vd = (float*)alloc(HH * sizeof(float));
    u16* Wt0 = (u16*)alloc(8192 * sizeof(u16));    // [128][64]
    u16* Wt1 = (u16*)alloc(16384 * sizeof(u16));   // [128][128]
    u16* Wt2 = (u16*)alloc(16384 * sizeof(u16));   // [128][128]
    u16* Wtr = (u16*)alloc(8192 * sizeof(u16));    // [64][128]
    u16* xb = (u16*)alloc((size_t)NN * FF * sizeof(u16));     // bf16(x)
    u16* xaggb = (u16*)alloc((size_t)NN * FF * sizeof(u16));  // bf16(Â x)
    u16* bufA = (u16*)alloc((size_t)NN * HH * sizeof(u16));
    u16* bufB = (u16*)alloc((size_t)NN * HH * sizeof(u16));

    hipMemsetAsync(cnt, 0, NN * sizeof(int), stream);
    hipMemsetAsync(cursor, 0, NN * sizeof(int), stream);

    count_k<<<(EE + 255) / 256, 256, 0, stream>>>(ecol, cnt);
    dinv1_k<<<(NN + 255) / 256, 256, 0, stream>>>(cnt, dinv1);
    chunksum_k<<<NCHUNK, 256, 0, stream>>>(cnt, chunk_sum);
    chunkoff_k<<<1, 64, 0, stream>>>(chunk_sum, chunk_off, col_ptr);
    colptr_k<<<NCHUNK, 256, 0, stream>>>(cnt, chunk_off, col_ptr);
    fill_k<<<(EE + 255) / 256, 256, 0, stream>>>(erow, ecol, col_ptr, cursor, dinv1,
                                                 csr_src, csr_w);
    cast_k<<<(NN * FF / 4 + 255) / 256, 256, 0, stream>>>(x, xb);
    gemv_vsvd_k<<<1, 128, 0, stream>>>(Wg, att_src, att_dst, vs, vd);
    prep_wt_k<<<192, 256, 0, stream>>>(W0, W1, W2, Wr, Wt0, Wt1, Wt2, Wtr);

    int aggGrid = (NN + 3) / 4;
    const int GG = 512;

    // layer 1: xagg = Â1 x  (128 B bf16 rows) ; x1 = relu(xagg@W0+b0) + fused a_s/a_d
    aggx_k<<<aggGrid, 256, 0, stream>>>(xb, col_ptr, csr_src, csr_w, dinv1, xaggb);
    gemm1_k<<<GG, 256, 0, stream>>>(xaggb, Wt0, b0, vs, vd, bufA, a_s, a_d);
    // attention
    attn_k<<<(NN + 31) / 32, 256, 0, stream>>>(col_ptr, csr_src, a_s, a_d, alpha, dinv2);
    w2_k<<<(EE + 255) / 256, 256, 0, stream>>>(csr_src, dinv2, alpha);
    // layer 2
    mfma_gemm_k<HH, HH, false><<<GG, 256, 0, stream>>>(bufA, Wt1, nullptr, bufB);
    agg2_k<<<aggGrid, 256, 0, stream>>>(bufB, col_ptr, csr_src, alpha, dinv2, b1, bufA);
    // layer 3
    mfma_gemm_k<HH, HH, false><<<GG, 256, 0, stream>>>(bufA, Wt2, nullptr, bufB);
    agg2_k<<<aggGrid, 256, 0, stream>>>(bufB, col_ptr, csr_src, alpha, dinv2, b2, bufA);
    // readout
    mfma_gemm_k<HH, FF, true><<<GG, 256, 0, stream>>>(bufA, Wtr, br, out);
}